// Round 18
// baseline (68.244 us; speedup 1.0000x reference)
//
#include <hip/hip_runtime.h>

#define N_NODES 50000
#define N_EDGES 800000
#define D 64
#define NB 196            // buckets; bucket = id >> 8; 196*256 = 50176 >= 50000
#define BSZ 256           // nodes per bucket
#define NSLICE 256        // edge slices == CU count; 256*3136 = 802816 >= 800000
#define SLICE_I4 784      // int4 groups per slice (3136 edges)
#define E4 (N_EDGES / 4)  // 200000 int4 groups
#define CAP 52            // entries per (slice,bucket) cell; mean 16, P(ovf)~5e-7
#define CELLW (NB * CAP)  // 10192 words per slice (40768 B, 16B-aligned)
#define LIN_BLK 782       // ceil(50000/64) linear tiles

// bf16 helpers (round-to-nearest-even); fp32 accumulation everywhere.
__device__ __forceinline__ ushort f2bf(float f) {
    unsigned u = __float_as_uint(f);
    unsigned r = u + 0x7fffu + ((u >> 16) & 1u);
    return (ushort)(r >> 16);
}
// acc[k] += bf16(a)[k] * s   (fp32 fma)
__device__ __forceinline__ void acc8s(const uint4 a, float s, float* acc) {
    acc[0] = fmaf(__uint_as_float(a.x << 16),         s, acc[0]);
    acc[1] = fmaf(__uint_as_float(a.x & 0xffff0000u), s, acc[1]);
    acc[2] = fmaf(__uint_as_float(a.y << 16),         s, acc[2]);
    acc[3] = fmaf(__uint_as_float(a.y & 0xffff0000u), s, acc[3]);
    acc[4] = fmaf(__uint_as_float(a.z << 16),         s, acc[4]);
    acc[5] = fmaf(__uint_as_float(a.z & 0xffff0000u), s, acc[5]);
    acc[6] = fmaf(__uint_as_float(a.w << 16),         s, acc[6]);
    acc[7] = fmaf(__uint_as_float(a.w & 0xffff0000u), s, acc[7]);
}

// ---------------------------------------------------------------------------
// K1 (fused, independent halves): blocks [0,NSLICE) = single-pass cell
// partition (LDS-staged, coalesced writeout — r17); blocks [NSLICE,+LIN_BLK)
// = UNSCALED linear h16u = bf16(x @ W^T + b), one 64-node tile per block,
// 1024 threads (thread = node x 4 strided outputs). The linear has no dep
// on the partition, so fusing overlaps the two instead of serializing.
// ---------------------------------------------------------------------------
__global__ __launch_bounds__(1024) void k1_kernel(
        const int* __restrict__ s, const int* __restrict__ r,
        const float* __restrict__ x, const float* __restrict__ w,
        const float* __restrict__ bias,
        unsigned* __restrict__ prc, unsigned char* __restrict__ psc,
        int* __restrict__ rcnt, int* __restrict__ scnt,
        ushort* __restrict__ h16u) {
    __shared__ char smem[52544];
    const int tid = threadIdx.x;

    if (blockIdx.x < NSLICE) {
        // ---- partition slice ----
        unsigned* lprc      = (unsigned*)smem;                  // 40768 B
        unsigned char* lpsc = (unsigned char*)(smem + 40768);   // 10192 B
        int* rcur           = (int*)(smem + 50960);             //   784 B
        int* scur           = (int*)(smem + 51744);             //   784 B
        const int sl = blockIdx.x;
        for (int i = tid; i < NB; i += 1024) { rcur[i] = 0; scur[i] = 0; }
        __syncthreads();

        int e4 = sl * SLICE_I4 + tid;
        if (tid < SLICE_I4 && e4 < E4) {
            int4 rv = ((const int4*)r)[e4];
            int4 sv = ((const int4*)s)[e4];
            int ri[4] = {rv.x, rv.y, rv.z, rv.w};
            int si[4] = {sv.x, sv.y, sv.z, sv.w};
            #pragma unroll
            for (int k = 0; k < 4; ++k) {
                int b = ri[k] >> 8;
                int pos = atomicAdd(&rcur[b], 1);
                if (pos < CAP)
                    lprc[b * CAP + pos] =
                        ((unsigned)(ri[k] & 255) << 16) | (unsigned)si[k];
                int bs = si[k] >> 8;
                int pos2 = atomicAdd(&scur[bs], 1);
                if (pos2 < CAP)
                    lpsc[bs * CAP + pos2] = (unsigned char)(si[k] & 255);
            }
        }
        __syncthreads();

        for (int i = tid; i < NB; i += 1024) {
            rcnt[sl * NB + i] = min(rcur[i], CAP);
            scnt[sl * NB + i] = min(scur[i], CAP);
        }
        uint4* gp = (uint4*)(prc + (size_t)sl * CELLW);
        const uint4* lp = (const uint4*)lprc;
        for (int i = tid; i < CELLW / 4; i += 1024) gp[i] = lp[i];
        uint4* gq = (uint4*)(psc + (size_t)sl * CELLW);
        const uint4* lq = (const uint4*)lpsc;
        for (int i = tid; i < CELLW / 16; i += 1024) gq[i] = lq[i];
        return;
    }

    // ---- linear tile (unscaled) ----
    float* wlds = (float*)smem;               // 64*68*4 = 17408 B
    float* xlds = (float*)(smem + 17408);     // 17408 B
    float* blds = (float*)(smem + 34816);     //   256 B
    const int tile = blockIdx.x - NSLICE;
    const int nb = tile * 64;

    {   // stage W: 1024 float4, one per thread
        int o = tid >> 4, k4 = tid & 15;
        float4 wv = ((const float4*)w)[tid];
        *(float4*)&wlds[o * 68 + k4 * 4] = wv;
    }
    if (tid < 64) blds[tid] = bias[tid];
    {   // stage x tile: 64 nodes x 16 float4
        int nl = tid >> 4, k4 = tid & 15;
        int n = nb + nl;
        float4 xv = (n < N_NODES) ? ((const float4*)x)[n * 16 + k4]
                                  : make_float4(0.f, 0.f, 0.f, 0.f);
        *(float4*)&xlds[nl * 68 + k4 * 4] = xv;
    }
    __syncthreads();

    const int nl = tid >> 4;          // node 0..63
    const int t15 = tid & 15;         // output rows t15 + 16j (2-way bank, free)
    float a0 = 0.f, a1 = 0.f, a2 = 0.f, a3 = 0.f;
    #pragma unroll 4
    for (int k4 = 0; k4 < 16; ++k4) {
        float4 xv = *(const float4*)&xlds[nl * 68 + k4 * 4];
        float4 w0 = *(const float4*)&wlds[(t15     ) * 68 + k4 * 4];
        float4 w1 = *(const float4*)&wlds[(t15 + 16) * 68 + k4 * 4];
        float4 w2 = *(const float4*)&wlds[(t15 + 32) * 68 + k4 * 4];
        float4 w3 = *(const float4*)&wlds[(t15 + 48) * 68 + k4 * 4];
        a0 += xv.x * w0.x + xv.y * w0.y + xv.z * w0.z + xv.w * w0.w;
        a1 += xv.x * w1.x + xv.y * w1.y + xv.z * w1.z + xv.w * w1.w;
        a2 += xv.x * w2.x + xv.y * w2.y + xv.z * w2.z + xv.w * w2.w;
        a3 += xv.x * w3.x + xv.y * w3.y + xv.z * w3.z + xv.w * w3.w;
    }
    int n = nb + nl;
    if (n < N_NODES) {
        h16u[n * D + t15     ] = f2bf(a0 + blds[t15     ]);
        h16u[n * D + t15 + 16] = f2bf(a1 + blds[t15 + 16]);
        h16u[n * D + t15 + 32] = f2bf(a2 + blds[t15 + 32]);
        h16u[n * D + t15 + 48] = f2bf(a3 + blds[t15 + 48]);
    }
}

// ---------------------------------------------------------------------------
// K2: blocks [0,NB) build per-bucket CSR from receiver cells; blocks
// [NB,2NB) compute sender-degree -> sscale (tiny now; linear moved to K1).
// ---------------------------------------------------------------------------
__global__ __launch_bounds__(256) void post_kernel(
        const unsigned* __restrict__ prc, const unsigned char* __restrict__ psc,
        const int* __restrict__ rcnt, const int* __restrict__ scnt,
        int* __restrict__ rowoff, ushort* __restrict__ csr16,
        float* __restrict__ sscale) {
    __shared__ int sc[256];
    __shared__ int h4[BSZ];
    const int tid = threadIdx.x;

    if (blockIdx.x >= NB) {
        // ---- sscale for sender bucket b ----
        const int b = blockIdx.x - NB;
        h4[tid] = 0;
        __syncthreads();
        {
            int sl = tid;                       // exactly one slice per thread
            int c = scnt[sl * NB + b];
            const unsigned char* cell = psc + (size_t)sl * CELLW + (size_t)b * CAP;
            for (int i = 0; i < c; ++i) atomicAdd(&h4[cell[i]], 1);
        }
        __syncthreads();
        int n = b * BSZ + tid;
        if (n < N_NODES) sscale[n] = rsqrtf((float)(h4[tid] + 1));  // +1 self
        return;
    }

    // ---- CSR for receiver bucket b ----
    const int b = blockIdx.x;
    int tot = 0;
    if (tid < NB) {
        for (int sl = 0; sl < NSLICE; ++sl) tot += rcnt[sl * NB + tid];
    }
    sc[tid] = tot;
    __syncthreads();
    for (int o = 1; o < 256; o <<= 1) {
        int u = (tid >= o) ? sc[tid - o] : 0;
        __syncthreads();
        sc[tid] += u;
        __syncthreads();
    }
    const int rb = (b == 0) ? 0 : sc[b - 1];
    __syncthreads();

    h4[tid] = 0;
    __syncthreads();
    {
        int sl = tid;
        int c = rcnt[sl * NB + b];
        const unsigned* cell = prc + (size_t)sl * CELLW + (size_t)b * CAP;
        for (int i = 0; i < c; ++i) atomicAdd(&h4[cell[i] >> 16], 1);
    }
    __syncthreads();

    int v = h4[tid];
    sc[tid] = v;
    __syncthreads();
    for (int o = 1; o < 256; o <<= 1) {
        int u = (tid >= o) ? sc[tid - o] : 0;
        __syncthreads();
        sc[tid] += u;
        __syncthreads();
    }
    int excl = sc[tid] - v;
    int n = b * BSZ + tid;
    if (n < N_NODES) rowoff[n] = rb + excl;
    h4[tid] = rb + excl;                 // reuse h4 as cursor array
    if (b == NB - 1 && tid == 0) rowoff[N_NODES] = N_EDGES;
    __syncthreads();

    {
        int sl = tid;
        int c = rcnt[sl * NB + b];
        const unsigned* cell = prc + (size_t)sl * CELLW + (size_t)b * CAP;
        for (int i = 0; i < c; ++i) {
            unsigned pw = cell[i];
            int pos = atomicAdd(&h4[pw >> 16], 1);
            csr16[pos] = (ushort)(pw & 0xffffu);
        }
    }
}

// ---------------------------------------------------------------------------
// K3: gather-accumulate with per-sender scale. Wave per node; 8-lane group
// per row, uint4 (8 bf16) + broadcast sscale[s] load + fp32 FMA. All __shfl
// with full wave active (r11 lesson).
// ---------------------------------------------------------------------------
__global__ __launch_bounds__(256) void gather_kernel(
        const ushort* __restrict__ h16u, const float* __restrict__ sscale,
        const int* __restrict__ rowoff, const ushort* __restrict__ csr16,
        float* __restrict__ out) {
    const int lane = threadIdx.x & 63;
    const int q = lane & 7;        // channel octet: channels q*8 .. q*8+7
    const int g = lane >> 3;       // edge sub-slot 0..7
    const int n = blockIdx.x * 4 + (threadIdx.x >> 6);
    if (n >= N_NODES) return;

    float acc[8];
    #pragma unroll
    for (int k = 0; k < 8; ++k) acc[k] = 0.f;

    const int base = rowoff[n];
    const int cnt = rowoff[n + 1] - base;

    for (int j0 = 0; j0 < cnt; j0 += 64) {
        int m = cnt - j0; if (m > 64) m = 64;
        int my = (lane < m) ? (int)csr16[base + j0 + lane] : 0;
        int t = 0;
        for (; t + 16 <= m; t += 16) {          // two full 8-edge slots
            int s0 = __shfl(my, t + g);
            int s1 = __shfl(my, t + 8 + g);
            uint4 a = *(const uint4*)&h16u[s0 * D + q * 8];
            uint4 b = *(const uint4*)&h16u[s1 * D + q * 8];
            float c0 = sscale[s0];              // broadcast within group
            float c1 = sscale[s1];
            acc8s(a, c0, acc);
            acc8s(b, c1, acc);
        }
        for (; t < m; t += 8) {                 // ragged tail slots
            int e = t + g;
            int ee = (e < m) ? e : 0;           // in-range source lane
            int s0 = __shfl(my, ee);            // executed by ALL lanes
            if (e < m) {
                uint4 a = *(const uint4*)&h16u[s0 * D + q * 8];
                acc8s(a, sscale[s0], acc);
            }
        }
    }

    // butterfly: afterwards every lane holds the full sums
    #pragma unroll
    for (int k = 0; k < 8; ++k) acc[k] += __shfl_xor(acc[k], 8);
    #pragma unroll
    for (int k = 0; k < 8; ++k) acc[k] += __shfl_xor(acc[k], 16);
    #pragma unroll
    for (int k = 0; k < 8; ++k) acc[k] += __shfl_xor(acc[k], 32);

    uint4 sv = *(const uint4*)&h16u[n * D + q * 8];
    acc8s(sv, sscale[n], acc);                  // self term
    float sc = rsqrtf((float)(cnt + 1));
    float o[8];
    #pragma unroll
    for (int k = 0; k < 8; ++k) {
        float vv = acc[k] * sc;
        o[k] = vv > 0.f ? vv : 0.01f * vv;
    }
    if (g == 0) {
        *(float4*)(out + n * D + q * 8)     = make_float4(o[0], o[1], o[2], o[3]);
    } else if (g == 1) {
        *(float4*)(out + n * D + q * 8 + 4) = make_float4(o[4], o[5], o[6], o[7]);
    }
}

// ---------------------------------------------------------------------------
extern "C" void kernel_launch(void* const* d_in, const int* in_sizes, int n_in,
                              void* d_out, int out_size, void* d_ws, size_t ws_size,
                              hipStream_t stream) {
    const float* x       = (const float*)d_in[0];
    const int*   senders = (const int*)d_in[1];
    const int*   recvs   = (const int*)d_in[2];
    const float* weight  = (const float*)d_in[3];
    const float* bias    = (const float*)d_in[4];
    float* out = (float*)d_out;

    // workspace layout (256B-aligned chunks), ~22 MB total
    char* p = (char*)d_ws;
    auto take = [&](size_t bytes) { char* q = p; p += (bytes + 255) & ~(size_t)255; return q; };
    ushort*        h16u   = (ushort*)take((size_t)N_NODES * D * 2);         // 6.4 MB
    float*         sscale = (float*)take((size_t)N_NODES * 4);              // 200 KB
    unsigned*      prc    = (unsigned*)take((size_t)NSLICE * CELLW * 4);    // 10.4 MB
    unsigned char* psc    = (unsigned char*)take((size_t)NSLICE * CELLW);   // 2.6 MB
    int*           rcnt   = (int*)take((size_t)NSLICE * NB * 4);            // 200 KB
    int*           scnt   = (int*)take((size_t)NSLICE * NB * 4);            // 200 KB
    int*           rowoff = (int*)take((size_t)(N_NODES + 1) * 4);          // 200 KB
    ushort*        csr16  = (ushort*)take((size_t)N_EDGES * 2);             // 1.6 MB

    hipLaunchKernelGGL(k1_kernel, dim3(NSLICE + LIN_BLK), dim3(1024), 0, stream,
                       senders, recvs, x, weight, bias,
                       prc, psc, rcnt, scnt, h16u);
    hipLaunchKernelGGL(post_kernel, dim3(2 * NB), dim3(BSZ), 0, stream,
                       prc, psc, rcnt, scnt, rowoff, csr16, sscale);
    hipLaunchKernelGGL(gather_kernel, dim3((N_NODES + 3) / 4), dim3(256), 0, stream,
                       h16u, sscale, rowoff, csr16, out);
}

// Round 19
// 64.218 us; speedup vs baseline: 1.0627x; 1.0627x over previous
//
#include <hip/hip_runtime.h>

#define N_NODES 50000
#define N_EDGES 800000
#define D 64
#define NB 196            // buckets; bucket = id >> 8; 196*256 = 50176 >= 50000
#define BSZ 256           // nodes per bucket
#define NSLICE 256        // edge slices == CU count; 256*3136 = 802816 >= 800000
#define SLICE_E 3136      // edges per slice (exact; last slice ragged)
#define SLICE_I4 784      // int4 groups per slice
#define E4 (N_EDGES / 4)  // 200000 int4 groups

// bf16 helpers (round-to-nearest-even); fp32 accumulation everywhere.
__device__ __forceinline__ ushort f2bf(float f) {
    unsigned u = __float_as_uint(f);
    unsigned r = u + 0x7fffu + ((u >> 16) & 1u);
    return (ushort)(r >> 16);
}
__device__ __forceinline__ void acc8(const uint4 a, float* acc) {
    acc[0] += __uint_as_float(a.x << 16);
    acc[1] += __uint_as_float(a.x & 0xffff0000u);
    acc[2] += __uint_as_float(a.y << 16);
    acc[3] += __uint_as_float(a.y & 0xffff0000u);
    acc[4] += __uint_as_float(a.z << 16);
    acc[5] += __uint_as_float(a.z & 0xffff0000u);
    acc[6] += __uint_as_float(a.w << 16);
    acc[7] += __uint_as_float(a.w & 0xffff0000u);
}

// ---------------------------------------------------------------------------
// K1: single-pass partition into COMPACT per-slice cells (r18 post-mortem:
// CAP-padded arrays wrote/read 13MB of which 4MB was live). Two-pass
// in-block counting sort: count -> LDS scan -> scatter compact; edges kept
// in registers between passes. Streams exactly 3136 words + 3136 bytes per
// slice, coalesced. LDS 19KB (was 52.5KB).
// ---------------------------------------------------------------------------
__global__ __launch_bounds__(1024) void part1_kernel(
        const int* __restrict__ s, const int* __restrict__ r,
        unsigned* __restrict__ prc, unsigned char* __restrict__ psc,
        int* __restrict__ rcnt, int* __restrict__ scnt,
        int* __restrict__ roffg, int* __restrict__ soffg) {
    __shared__ unsigned lprc[SLICE_E];        // 12544 B compact receiver cells
    __shared__ unsigned char lpsc[SLICE_E];   //  3136 B compact sender cells
    __shared__ int rcur[NB], scur[NB];        // counts (preserved)
    __shared__ int rof[NB], sof[NB];          // scan -> cursors
    __shared__ int sc[256];
    const int tid = threadIdx.x, sl = blockIdx.x;
    for (int i = tid; i < NB; i += 1024) { rcur[i] = 0; scur[i] = 0; }
    __syncthreads();

    int e4 = sl * SLICE_I4 + tid;
    const bool act = (tid < SLICE_I4) && (e4 < E4);
    int4 rv, sv;
    if (act) {
        rv = ((const int4*)r)[e4];
        sv = ((const int4*)s)[e4];
        atomicAdd(&rcur[rv.x >> 8], 1); atomicAdd(&rcur[rv.y >> 8], 1);
        atomicAdd(&rcur[rv.z >> 8], 1); atomicAdd(&rcur[rv.w >> 8], 1);
        atomicAdd(&scur[sv.x >> 8], 1); atomicAdd(&scur[sv.y >> 8], 1);
        atomicAdd(&scur[sv.z >> 8], 1); atomicAdd(&scur[sv.w >> 8], 1);
    }
    __syncthreads();

    // exclusive scan of receiver counts
    int v = 0;
    if (tid < 256) { v = (tid < NB) ? rcur[tid] : 0; sc[tid] = v; }
    __syncthreads();
    for (int o = 1; o < 256; o <<= 1) {
        int u = 0;
        if (tid < 256 && tid >= o) u = sc[tid - o];
        __syncthreads();
        if (tid < 256) sc[tid] += u;
        __syncthreads();
    }
    if (tid < NB) rof[tid] = sc[tid] - v;
    __syncthreads();
    // exclusive scan of sender counts
    int v2 = 0;
    if (tid < 256) { v2 = (tid < NB) ? scur[tid] : 0; sc[tid] = v2; }
    __syncthreads();
    for (int o = 1; o < 256; o <<= 1) {
        int u = 0;
        if (tid < 256 && tid >= o) u = sc[tid - o];
        __syncthreads();
        if (tid < 256) sc[tid] += u;
        __syncthreads();
    }
    if (tid < NB) sof[tid] = sc[tid] - v2;
    __syncthreads();

    // persist counts + offsets before cursors are destroyed
    if (tid < NB) {
        rcnt[sl * NB + tid] = rcur[tid];
        scnt[sl * NB + tid] = scur[tid];
        roffg[sl * NB + tid] = rof[tid];
        soffg[sl * NB + tid] = sof[tid];
    }
    __syncthreads();

    // pass B: scatter into compact LDS via cursor atomics
    if (act) {
        int ri[4] = {rv.x, rv.y, rv.z, rv.w};
        int si[4] = {sv.x, sv.y, sv.z, sv.w};
        #pragma unroll
        for (int k = 0; k < 4; ++k) {
            int pos = atomicAdd(&rof[ri[k] >> 8], 1);
            lprc[pos] = ((unsigned)(ri[k] & 255) << 16) | (unsigned)si[k];
            int pos2 = atomicAdd(&sof[si[k] >> 8], 1);
            lpsc[pos2] = (unsigned char)(si[k] & 255);
        }
    }
    __syncthreads();

    // coalesced compact writeout
    if (tid < SLICE_I4)
        ((uint4*)(prc + (size_t)sl * SLICE_E))[tid] = ((const uint4*)lprc)[tid];
    if (tid < SLICE_E / 16)
        ((uint4*)(psc + (size_t)sl * SLICE_E))[tid] = ((const uint4*)lpsc)[tid];
}

// ---------------------------------------------------------------------------
// K2 (merged, r17 structure): blocks [0,NB) build per-bucket CSR; blocks
// [NB,2NB) compute sender-degree scales in LDS and IMMEDIATELY run the
// linear (x @ W^T + b) * scale for their 256 nodes (4 x 64-node LDS tiles).
// Compact-cell indexing via roffg/soffg.
// ---------------------------------------------------------------------------
__global__ __launch_bounds__(256, 4) void post_kernel(
        const unsigned* __restrict__ prc, const unsigned char* __restrict__ psc,
        const int* __restrict__ rcnt, const int* __restrict__ scnt,
        const int* __restrict__ roffg, const int* __restrict__ soffg,
        int* __restrict__ rowoff, ushort* __restrict__ csr16,
        const float* __restrict__ x, const float* __restrict__ w,
        const float* __restrict__ bias, ushort* __restrict__ h16) {
    __shared__ int sc[256];
    __shared__ int h4[BSZ];
    __shared__ float wlds[64 * 68];   // W staged (padded rows)
    __shared__ float xlds[64 * 68];   // x tile
    __shared__ float slds[BSZ];       // per-node scale
    __shared__ float blds[64];        // bias
    const int tid = threadIdx.x;

    if (blockIdx.x >= NB) {
        // ---- sscale + linear for sender bucket b ----
        const int b = blockIdx.x - NB;
        h4[tid] = 0;
        if (tid < 64) blds[tid] = bias[tid];
        __syncthreads();
        {
            int sl = tid;                       // exactly one slice per thread
            int c = scnt[sl * NB + b];
            const unsigned char* cell = psc + (size_t)sl * SLICE_E + soffg[sl * NB + b];
            for (int i = 0; i < c; ++i) atomicAdd(&h4[cell[i]], 1);
        }
        __syncthreads();
        slds[tid] = rsqrtf((float)(h4[tid] + 1));   // +1 self edge
        // stage W once: 1024 float4
        #pragma unroll
        for (int q = 0; q < 4; ++q) {
            int idx = q * 256 + tid;
            int o = idx >> 4, k4 = idx & 15;
            float4 wv = ((const float4*)w)[idx];
            *(float4*)&wlds[o * 68 + k4 * 4] = wv;
        }
        __syncthreads();

        const int t15 = tid & 15;
        const int g = tid >> 4;           // 0..15: node group (4 nodes each)
        for (int tile = 0; tile < 4; ++tile) {
            const int nb = b * BSZ + tile * 64;
            // stage x tile: 64 nodes x 16 float4
            #pragma unroll
            for (int q = 0; q < 4; ++q) {
                int idx = q * 256 + tid;
                int nl = idx >> 4, k4 = idx & 15;
                int n = nb + nl;
                float4 xv = (n < N_NODES) ? ((const float4*)x)[n * 16 + k4]
                                          : make_float4(0.f, 0.f, 0.f, 0.f);
                *(float4*)&xlds[nl * 68 + k4 * 4] = xv;
            }
            __syncthreads();

            float acc[4][4];
            #pragma unroll
            for (int i = 0; i < 4; ++i)
                #pragma unroll
                for (int j = 0; j < 4; ++j) acc[i][j] = 0.f;

            #pragma unroll 2
            for (int k4 = 0; k4 < 16; ++k4) {
                float4 wv0 = *(const float4*)&wlds[(t15     ) * 68 + k4 * 4];
                float4 wv1 = *(const float4*)&wlds[(t15 + 16) * 68 + k4 * 4];
                float4 wv2 = *(const float4*)&wlds[(t15 + 32) * 68 + k4 * 4];
                float4 wv3 = *(const float4*)&wlds[(t15 + 48) * 68 + k4 * 4];
                #pragma unroll
                for (int i = 0; i < 4; ++i) {
                    float4 xv = *(const float4*)&xlds[(g * 4 + i) * 68 + k4 * 4];
                    acc[i][0] += xv.x * wv0.x + xv.y * wv0.y + xv.z * wv0.z + xv.w * wv0.w;
                    acc[i][1] += xv.x * wv1.x + xv.y * wv1.y + xv.z * wv1.z + xv.w * wv1.w;
                    acc[i][2] += xv.x * wv2.x + xv.y * wv2.y + xv.z * wv2.z + xv.w * wv2.w;
                    acc[i][3] += xv.x * wv3.x + xv.y * wv3.y + xv.z * wv3.z + xv.w * wv3.w;
                }
            }

            #pragma unroll
            for (int i = 0; i < 4; ++i) {
                int nl = g * 4 + i;
                int n = nb + nl;
                if (n < N_NODES) {
                    float scl = slds[tile * 64 + nl];
                    h16[n * D + t15     ] = f2bf((acc[i][0] + blds[t15     ]) * scl);
                    h16[n * D + t15 + 16] = f2bf((acc[i][1] + blds[t15 + 16]) * scl);
                    h16[n * D + t15 + 32] = f2bf((acc[i][2] + blds[t15 + 32]) * scl);
                    h16[n * D + t15 + 48] = f2bf((acc[i][3] + blds[t15 + 48]) * scl);
                }
            }
            __syncthreads();   // xlds reused next tile
        }
        return;
    }

    // ---- CSR for receiver bucket b ----
    const int b = blockIdx.x;
    // bucket totals (coalesced across tid) + scan
    int tot = 0;
    if (tid < NB) {
        for (int sl = 0; sl < NSLICE; ++sl) tot += rcnt[sl * NB + tid];
    }
    sc[tid] = tot;
    __syncthreads();
    for (int o = 1; o < 256; o <<= 1) {
        int u = (tid >= o) ? sc[tid - o] : 0;
        __syncthreads();
        sc[tid] += u;
        __syncthreads();
    }
    const int rb = (b == 0) ? 0 : sc[b - 1];
    __syncthreads();

    // node-level hist (one slice-cell per thread)
    h4[tid] = 0;
    __syncthreads();
    {
        int sl = tid;
        int c = rcnt[sl * NB + b];
        const unsigned* cell = prc + (size_t)sl * SLICE_E + roffg[sl * NB + b];
        for (int i = 0; i < c; ++i) atomicAdd(&h4[cell[i] >> 16], 1);
    }
    __syncthreads();

    // node scan -> rowoff + cursors
    int v = h4[tid];
    sc[tid] = v;
    __syncthreads();
    for (int o = 1; o < 256; o <<= 1) {
        int u = (tid >= o) ? sc[tid - o] : 0;
        __syncthreads();
        sc[tid] += u;
        __syncthreads();
    }
    int excl = sc[tid] - v;
    int n = b * BSZ + tid;
    if (n < N_NODES) rowoff[n] = rb + excl;
    h4[tid] = rb + excl;                 // reuse h4 as cursor array
    if (b == NB - 1 && tid == 0) rowoff[N_NODES] = N_EDGES;
    __syncthreads();

    // scatter senders into per-node csr (one slice-cell per thread)
    {
        int sl = tid;
        int c = rcnt[sl * NB + b];
        const unsigned* cell = prc + (size_t)sl * SLICE_E + roffg[sl * NB + b];
        for (int i = 0; i < c; ++i) {
            unsigned pw = cell[i];
            int pos = atomicAdd(&h4[pw >> 16], 1);
            csr16[pos] = (ushort)(pw & 0xffffu);
        }
    }
}

// ---------------------------------------------------------------------------
// K3: gather-accumulate, wide-load layout. Wave per node; 8-lane group per
// row, uint4 (8 bf16) per lane. All __shfl calls run with the full wave
// active (r11 lesson: divergent shfl w/ inactive source lane is undefined).
// ---------------------------------------------------------------------------
__global__ __launch_bounds__(256) void gather_kernel(
        const ushort* __restrict__ h16, const int* __restrict__ rowoff,
        const ushort* __restrict__ csr16, float* __restrict__ out) {
    const int lane = threadIdx.x & 63;
    const int q = lane & 7;        // channel octet: channels q*8 .. q*8+7
    const int g = lane >> 3;       // edge sub-slot 0..7
    const int n = blockIdx.x * 4 + (threadIdx.x >> 6);
    if (n >= N_NODES) return;

    float acc[8];
    #pragma unroll
    for (int k = 0; k < 8; ++k) acc[k] = 0.f;

    const int base = rowoff[n];
    const int cnt = rowoff[n + 1] - base;

    for (int j0 = 0; j0 < cnt; j0 += 64) {
        int m = cnt - j0; if (m > 64) m = 64;
        int my = (lane < m) ? (int)csr16[base + j0 + lane] : 0;
        int t = 0;
        for (; t + 16 <= m; t += 16) {          // two full 8-edge slots
            int s0 = __shfl(my, t + g);
            int s1 = __shfl(my, t + 8 + g);
            uint4 a = *(const uint4*)&h16[s0 * D + q * 8];
            uint4 b = *(const uint4*)&h16[s1 * D + q * 8];
            acc8(a, acc);
            acc8(b, acc);
        }
        for (; t < m; t += 8) {                 // ragged tail slots
            int e = t + g;
            int ee = (e < m) ? e : 0;           // in-range source lane
            int s0 = __shfl(my, ee);            // executed by ALL lanes
            if (e < m) {
                uint4 a = *(const uint4*)&h16[s0 * D + q * 8];
                acc8(a, acc);
            }
        }
    }

    // butterfly: afterwards every lane holds the full sums
    #pragma unroll
    for (int k = 0; k < 8; ++k) acc[k] += __shfl_xor(acc[k], 8);
    #pragma unroll
    for (int k = 0; k < 8; ++k) acc[k] += __shfl_xor(acc[k], 16);
    #pragma unroll
    for (int k = 0; k < 8; ++k) acc[k] += __shfl_xor(acc[k], 32);

    uint4 sv = *(const uint4*)&h16[n * D + q * 8];
    acc8(sv, acc);
    float sc = rsqrtf((float)(cnt + 1));
    float o[8];
    #pragma unroll
    for (int k = 0; k < 8; ++k) {
        float vv = acc[k] * sc;
        o[k] = vv > 0.f ? vv : 0.01f * vv;
    }
    if (g == 0) {
        *(float4*)(out + n * D + q * 8)     = make_float4(o[0], o[1], o[2], o[3]);
    } else if (g == 1) {
        *(float4*)(out + n * D + q * 8 + 4) = make_float4(o[4], o[5], o[6], o[7]);
    }
}

// ---------------------------------------------------------------------------
extern "C" void kernel_launch(void* const* d_in, const int* in_sizes, int n_in,
                              void* d_out, int out_size, void* d_ws, size_t ws_size,
                              hipStream_t stream) {
    const float* x       = (const float*)d_in[0];
    const int*   senders = (const int*)d_in[1];
    const int*   recvs   = (const int*)d_in[2];
    const float* weight  = (const float*)d_in[3];
    const float* bias    = (const float*)d_in[4];
    float* out = (float*)d_out;

    // workspace layout (256B-aligned chunks), ~14 MB total
    char* p = (char*)d_ws;
    auto take = [&](size_t bytes) { char* q = p; p += (bytes + 255) & ~(size_t)255; return q; };
    ushort*        h16    = (ushort*)take((size_t)N_NODES * D * 2);         // 6.4 MB
    unsigned*      prc    = (unsigned*)take((size_t)NSLICE * SLICE_E * 4);  // 3.2 MB
    unsigned char* psc    = (unsigned char*)take((size_t)NSLICE * SLICE_E); // 0.8 MB
    int*           rcnt   = (int*)take((size_t)NSLICE * NB * 4);            // 200 KB
    int*           scnt   = (int*)take((size_t)NSLICE * NB * 4);            // 200 KB
    int*           roffg  = (int*)take((size_t)NSLICE * NB * 4);            // 200 KB
    int*           soffg  = (int*)take((size_t)NSLICE * NB * 4);            // 200 KB
    int*           rowoff = (int*)take((size_t)(N_NODES + 1) * 4);          // 200 KB
    ushort*        csr16  = (ushort*)take((size_t)N_EDGES * 2);             // 1.6 MB

    hipLaunchKernelGGL(part1_kernel, dim3(NSLICE), dim3(1024), 0, stream,
                       senders, recvs, prc, psc, rcnt, scnt, roffg, soffg);
    hipLaunchKernelGGL(post_kernel, dim3(2 * NB), dim3(BSZ), 0, stream,
                       prc, psc, rcnt, scnt, roffg, soffg, rowoff, csr16,
                       x, weight, bias, h16);
    hipLaunchKernelGGL(gather_kernel, dim3((N_NODES + 3) / 4), dim3(256), 0, stream,
                       h16, rowoff, csr16, out);
}

// Round 20
// 63.041 us; speedup vs baseline: 1.0825x; 1.0187x over previous
//
#include <hip/hip_runtime.h>

#define N_NODES 50000
#define N_EDGES 800000
#define D 64
#define NB 196            // buckets; bucket = id >> 8; 196*256 = 50176 >= 50000
#define BSZ 256           // nodes per bucket
#define NSLICE 256        // edge slices == CU count; 256*3136 = 802816 >= 800000
#define SLICE_E 3136      // edges per slice (exact; last slice ragged)
#define SLICE_I4 784      // int4 groups per slice
#define E4 (N_EDGES / 4)  // 200000 int4 groups

// bf16 helpers (round-to-nearest-even); fp32 accumulation everywhere.
__device__ __forceinline__ ushort f2bf(float f) {
    unsigned u = __float_as_uint(f);
    unsigned r = u + 0x7fffu + ((u >> 16) & 1u);
    return (ushort)(r >> 16);
}
__device__ __forceinline__ void acc8(const uint4 a, float* acc) {
    acc[0] += __uint_as_float(a.x << 16);
    acc[1] += __uint_as_float(a.x & 0xffff0000u);
    acc[2] += __uint_as_float(a.y << 16);
    acc[3] += __uint_as_float(a.y & 0xffff0000u);
    acc[4] += __uint_as_float(a.z << 16);
    acc[5] += __uint_as_float(a.z & 0xffff0000u);
    acc[6] += __uint_as_float(a.w << 16);
    acc[7] += __uint_as_float(a.w & 0xffff0000u);
}

// ---------------------------------------------------------------------------
// K1: single-pass partition into COMPACT per-slice cells. r19 post-mortem:
// the block-wide Hillis-Steele scans cost ~64 barriers; replaced with two
// CONCURRENT single-wave shfl scans (wave 0: rcur->rof, wave 1: scur->sof;
// lane owns 4 buckets, 6 shfl_up rounds, zero block barriers).
// ---------------------------------------------------------------------------
__global__ __launch_bounds__(1024) void part1_kernel(
        const int* __restrict__ s, const int* __restrict__ r,
        unsigned* __restrict__ prc, unsigned char* __restrict__ psc,
        int* __restrict__ rcnt, int* __restrict__ scnt,
        int* __restrict__ roffg, int* __restrict__ soffg) {
    __shared__ unsigned lprc[SLICE_E];        // 12544 B compact receiver cells
    __shared__ unsigned char lpsc[SLICE_E];   //  3136 B compact sender cells
    __shared__ int rcur[NB], scur[NB];        // counts (preserved)
    __shared__ int rof[NB], sof[NB];          // offsets -> cursors
    const int tid = threadIdx.x, sl = blockIdx.x;
    for (int i = tid; i < NB; i += 1024) { rcur[i] = 0; scur[i] = 0; }
    __syncthreads();

    int e4 = sl * SLICE_I4 + tid;
    const bool act = (tid < SLICE_I4) && (e4 < E4);
    int4 rv, sv;
    if (act) {
        rv = ((const int4*)r)[e4];
        sv = ((const int4*)s)[e4];
        atomicAdd(&rcur[rv.x >> 8], 1); atomicAdd(&rcur[rv.y >> 8], 1);
        atomicAdd(&rcur[rv.z >> 8], 1); atomicAdd(&rcur[rv.w >> 8], 1);
        atomicAdd(&scur[sv.x >> 8], 1); atomicAdd(&scur[sv.y >> 8], 1);
        atomicAdd(&scur[sv.z >> 8], 1); atomicAdd(&scur[sv.w >> 8], 1);
    }
    __syncthreads();

    // two concurrent single-wave exclusive scans (no block barriers)
    {
        const int wv = tid >> 6, lane = tid & 63;
        if (wv < 2) {
            const int* cnt = wv ? scur : rcur;
            int* off = wv ? sof : rof;
            const int base = lane * 4;
            int c0 = (base + 0 < NB) ? cnt[base + 0] : 0;
            int c1 = (base + 1 < NB) ? cnt[base + 1] : 0;
            int c2 = (base + 2 < NB) ? cnt[base + 2] : 0;
            int c3 = (base + 3 < NB) ? cnt[base + 3] : 0;
            int sum = c0 + c1 + c2 + c3;
            int sv_ = sum;
            #pragma unroll
            for (int o = 1; o < 64; o <<= 1) {
                int u = __shfl_up(sv_, o);
                if (lane >= o) sv_ += u;
            }
            int excl = sv_ - sum;
            if (base + 0 < NB) off[base + 0] = excl;
            if (base + 1 < NB) off[base + 1] = excl + c0;
            if (base + 2 < NB) off[base + 2] = excl + c0 + c1;
            if (base + 3 < NB) off[base + 3] = excl + c0 + c1 + c2;
        }
    }
    __syncthreads();

    // persist counts + offsets before cursors are destroyed
    if (tid < NB) {
        rcnt[sl * NB + tid] = rcur[tid];
        scnt[sl * NB + tid] = scur[tid];
        roffg[sl * NB + tid] = rof[tid];
        soffg[sl * NB + tid] = sof[tid];
    }
    __syncthreads();

    // pass B: scatter into compact LDS via cursor atomics
    if (act) {
        int ri[4] = {rv.x, rv.y, rv.z, rv.w};
        int si[4] = {sv.x, sv.y, sv.z, sv.w};
        #pragma unroll
        for (int k = 0; k < 4; ++k) {
            int pos = atomicAdd(&rof[ri[k] >> 8], 1);
            lprc[pos] = ((unsigned)(ri[k] & 255) << 16) | (unsigned)si[k];
            int pos2 = atomicAdd(&sof[si[k] >> 8], 1);
            lpsc[pos2] = (unsigned char)(si[k] & 255);
        }
    }
    __syncthreads();

    // coalesced compact writeout
    if (tid < SLICE_I4)
        ((uint4*)(prc + (size_t)sl * SLICE_E))[tid] = ((const uint4*)lprc)[tid];
    if (tid < SLICE_E / 16)
        ((uint4*)(psc + (size_t)sl * SLICE_E))[tid] = ((const uint4*)lpsc)[tid];
}

// ---------------------------------------------------------------------------
// K2 (merged, r17 structure): blocks [0,NB) build per-bucket CSR; blocks
// [NB,2NB) compute sender-degree scales in LDS and IMMEDIATELY run the
// linear (x @ W^T + b) * scale for their 256 nodes (4 x 64-node LDS tiles).
// Compact-cell indexing via roffg/soffg.
// ---------------------------------------------------------------------------
__global__ __launch_bounds__(256, 4) void post_kernel(
        const unsigned* __restrict__ prc, const unsigned char* __restrict__ psc,
        const int* __restrict__ rcnt, const int* __restrict__ scnt,
        const int* __restrict__ roffg, const int* __restrict__ soffg,
        int* __restrict__ rowoff, ushort* __restrict__ csr16,
        const float* __restrict__ x, const float* __restrict__ w,
        const float* __restrict__ bias, ushort* __restrict__ h16) {
    __shared__ int sc[256];
    __shared__ int h4[BSZ];
    __shared__ float wlds[64 * 68];   // W staged (padded rows)
    __shared__ float xlds[64 * 68];   // x tile
    __shared__ float slds[BSZ];       // per-node scale
    __shared__ float blds[64];        // bias
    const int tid = threadIdx.x;

    if (blockIdx.x >= NB) {
        // ---- sscale + linear for sender bucket b ----
        const int b = blockIdx.x - NB;
        h4[tid] = 0;
        if (tid < 64) blds[tid] = bias[tid];
        __syncthreads();
        {
            int sl = tid;                       // exactly one slice per thread
            int c = scnt[sl * NB + b];
            const unsigned char* cell = psc + (size_t)sl * SLICE_E + soffg[sl * NB + b];
            for (int i = 0; i < c; ++i) atomicAdd(&h4[cell[i]], 1);
        }
        __syncthreads();
        slds[tid] = rsqrtf((float)(h4[tid] + 1));   // +1 self edge
        // stage W once: 1024 float4
        #pragma unroll
        for (int q = 0; q < 4; ++q) {
            int idx = q * 256 + tid;
            int o = idx >> 4, k4 = idx & 15;
            float4 wv = ((const float4*)w)[idx];
            *(float4*)&wlds[o * 68 + k4 * 4] = wv;
        }
        __syncthreads();

        const int t15 = tid & 15;
        const int g = tid >> 4;           // 0..15: node group (4 nodes each)
        for (int tile = 0; tile < 4; ++tile) {
            const int nb = b * BSZ + tile * 64;
            // stage x tile: 64 nodes x 16 float4
            #pragma unroll
            for (int q = 0; q < 4; ++q) {
                int idx = q * 256 + tid;
                int nl = idx >> 4, k4 = idx & 15;
                int n = nb + nl;
                float4 xv = (n < N_NODES) ? ((const float4*)x)[n * 16 + k4]
                                          : make_float4(0.f, 0.f, 0.f, 0.f);
                *(float4*)&xlds[nl * 68 + k4 * 4] = xv;
            }
            __syncthreads();

            float acc[4][4];
            #pragma unroll
            for (int i = 0; i < 4; ++i)
                #pragma unroll
                for (int j = 0; j < 4; ++j) acc[i][j] = 0.f;

            #pragma unroll 2
            for (int k4 = 0; k4 < 16; ++k4) {
                float4 wv0 = *(const float4*)&wlds[(t15     ) * 68 + k4 * 4];
                float4 wv1 = *(const float4*)&wlds[(t15 + 16) * 68 + k4 * 4];
                float4 wv2 = *(const float4*)&wlds[(t15 + 32) * 68 + k4 * 4];
                float4 wv3 = *(const float4*)&wlds[(t15 + 48) * 68 + k4 * 4];
                #pragma unroll
                for (int i = 0; i < 4; ++i) {
                    float4 xv = *(const float4*)&xlds[(g * 4 + i) * 68 + k4 * 4];
                    acc[i][0] += xv.x * wv0.x + xv.y * wv0.y + xv.z * wv0.z + xv.w * wv0.w;
                    acc[i][1] += xv.x * wv1.x + xv.y * wv1.y + xv.z * wv1.z + xv.w * wv1.w;
                    acc[i][2] += xv.x * wv2.x + xv.y * wv2.y + xv.z * wv2.z + xv.w * wv2.w;
                    acc[i][3] += xv.x * wv3.x + xv.y * wv3.y + xv.z * wv3.z + xv.w * wv3.w;
                }
            }

            #pragma unroll
            for (int i = 0; i < 4; ++i) {
                int nl = g * 4 + i;
                int n = nb + nl;
                if (n < N_NODES) {
                    float scl = slds[tile * 64 + nl];
                    h16[n * D + t15     ] = f2bf((acc[i][0] + blds[t15     ]) * scl);
                    h16[n * D + t15 + 16] = f2bf((acc[i][1] + blds[t15 + 16]) * scl);
                    h16[n * D + t15 + 32] = f2bf((acc[i][2] + blds[t15 + 32]) * scl);
                    h16[n * D + t15 + 48] = f2bf((acc[i][3] + blds[t15 + 48]) * scl);
                }
            }
            __syncthreads();   // xlds reused next tile
        }
        return;
    }

    // ---- CSR for receiver bucket b ----
    const int b = blockIdx.x;
    // bucket totals (coalesced across tid) + scan
    int tot = 0;
    if (tid < NB) {
        for (int sl = 0; sl < NSLICE; ++sl) tot += rcnt[sl * NB + tid];
    }
    sc[tid] = tot;
    __syncthreads();
    for (int o = 1; o < 256; o <<= 1) {
        int u = (tid >= o) ? sc[tid - o] : 0;
        __syncthreads();
        sc[tid] += u;
        __syncthreads();
    }
    const int rb = (b == 0) ? 0 : sc[b - 1];
    __syncthreads();

    // node-level hist (one slice-cell per thread)
    h4[tid] = 0;
    __syncthreads();
    {
        int sl = tid;
        int c = rcnt[sl * NB + b];
        const unsigned* cell = prc + (size_t)sl * SLICE_E + roffg[sl * NB + b];
        for (int i = 0; i < c; ++i) atomicAdd(&h4[cell[i] >> 16], 1);
    }
    __syncthreads();

    // node scan -> rowoff + cursors
    int v = h4[tid];
    sc[tid] = v;
    __syncthreads();
    for (int o = 1; o < 256; o <<= 1) {
        int u = (tid >= o) ? sc[tid - o] : 0;
        __syncthreads();
        sc[tid] += u;
        __syncthreads();
    }
    int excl = sc[tid] - v;
    int n = b * BSZ + tid;
    if (n < N_NODES) rowoff[n] = rb + excl;
    h4[tid] = rb + excl;                 // reuse h4 as cursor array
    if (b == NB - 1 && tid == 0) rowoff[N_NODES] = N_EDGES;
    __syncthreads();

    // scatter senders into per-node csr (one slice-cell per thread)
    {
        int sl = tid;
        int c = rcnt[sl * NB + b];
        const unsigned* cell = prc + (size_t)sl * SLICE_E + roffg[sl * NB + b];
        for (int i = 0; i < c; ++i) {
            unsigned pw = cell[i];
            int pos = atomicAdd(&h4[pw >> 16], 1);
            csr16[pos] = (ushort)(pw & 0xffffu);
        }
    }
}

// ---------------------------------------------------------------------------
// K3: gather-accumulate, wide-load layout. Wave per node; 8-lane group per
// row, uint4 (8 bf16) per lane. All __shfl calls run with the full wave
// active (r11 lesson: divergent shfl w/ inactive source lane is undefined).
// ---------------------------------------------------------------------------
__global__ __launch_bounds__(256) void gather_kernel(
        const ushort* __restrict__ h16, const int* __restrict__ rowoff,
        const ushort* __restrict__ csr16, float* __restrict__ out) {
    const int lane = threadIdx.x & 63;
    const int q = lane & 7;        // channel octet: channels q*8 .. q*8+7
    const int g = lane >> 3;       // edge sub-slot 0..7
    const int n = blockIdx.x * 4 + (threadIdx.x >> 6);
    if (n >= N_NODES) return;

    float acc[8];
    #pragma unroll
    for (int k = 0; k < 8; ++k) acc[k] = 0.f;

    const int base = rowoff[n];
    const int cnt = rowoff[n + 1] - base;

    for (int j0 = 0; j0 < cnt; j0 += 64) {
        int m = cnt - j0; if (m > 64) m = 64;
        int my = (lane < m) ? (int)csr16[base + j0 + lane] : 0;
        int t = 0;
        for (; t + 16 <= m; t += 16) {          // two full 8-edge slots
            int s0 = __shfl(my, t + g);
            int s1 = __shfl(my, t + 8 + g);
            uint4 a = *(const uint4*)&h16[s0 * D + q * 8];
            uint4 b = *(const uint4*)&h16[s1 * D + q * 8];
            acc8(a, acc);
            acc8(b, acc);
        }
        for (; t < m; t += 8) {                 // ragged tail slots
            int e = t + g;
            int ee = (e < m) ? e : 0;           // in-range source lane
            int s0 = __shfl(my, ee);            // executed by ALL lanes
            if (e < m) {
                uint4 a = *(const uint4*)&h16[s0 * D + q * 8];
                acc8(a, acc);
            }
        }
    }

    // butterfly: afterwards every lane holds the full sums
    #pragma unroll
    for (int k = 0; k < 8; ++k) acc[k] += __shfl_xor(acc[k], 8);
    #pragma unroll
    for (int k = 0; k < 8; ++k) acc[k] += __shfl_xor(acc[k], 16);
    #pragma unroll
    for (int k = 0; k < 8; ++k) acc[k] += __shfl_xor(acc[k], 32);

    uint4 sv = *(const uint4*)&h16[n * D + q * 8];
    acc8(sv, acc);
    float sc = rsqrtf((float)(cnt + 1));
    float o[8];
    #pragma unroll
    for (int k = 0; k < 8; ++k) {
        float vv = acc[k] * sc;
        o[k] = vv > 0.f ? vv : 0.01f * vv;
    }
    if (g == 0) {
        *(float4*)(out + n * D + q * 8)     = make_float4(o[0], o[1], o[2], o[3]);
    } else if (g == 1) {
        *(float4*)(out + n * D + q * 8 + 4) = make_float4(o[4], o[5], o[6], o[7]);
    }
}

// ---------------------------------------------------------------------------
extern "C" void kernel_launch(void* const* d_in, const int* in_sizes, int n_in,
                              void* d_out, int out_size, void* d_ws, size_t ws_size,
                              hipStream_t stream) {
    const float* x       = (const float*)d_in[0];
    const int*   senders = (const int*)d_in[1];
    const int*   recvs   = (const int*)d_in[2];
    const float* weight  = (const float*)d_in[3];
    const float* bias    = (const float*)d_in[4];
    float* out = (float*)d_out;

    // workspace layout (256B-aligned chunks), ~14 MB total
    char* p = (char*)d_ws;
    auto take = [&](size_t bytes) { char* q = p; p += (bytes + 255) & ~(size_t)255; return q; };
    ushort*        h16    = (ushort*)take((size_t)N_NODES * D * 2);         // 6.4 MB
    unsigned*      prc    = (unsigned*)take((size_t)NSLICE * SLICE_E * 4);  // 3.2 MB
    unsigned char* psc    = (unsigned char*)take((size_t)NSLICE * SLICE_E); // 0.8 MB
    int*           rcnt   = (int*)take((size_t)NSLICE * NB * 4);            // 200 KB
    int*           scnt   = (int*)take((size_t)NSLICE * NB * 4);            // 200 KB
    int*           roffg  = (int*)take((size_t)NSLICE * NB * 4);            // 200 KB
    int*           soffg  = (int*)take((size_t)NSLICE * NB * 4);            // 200 KB
    int*           rowoff = (int*)take((size_t)(N_NODES + 1) * 4);          // 200 KB
    ushort*        csr16  = (ushort*)take((size_t)N_EDGES * 2);             // 1.6 MB

    hipLaunchKernelGGL(part1_kernel, dim3(NSLICE), dim3(1024), 0, stream,
                       senders, recvs, prc, psc, rcnt, scnt, roffg, soffg);
    hipLaunchKernelGGL(post_kernel, dim3(2 * NB), dim3(BSZ), 0, stream,
                       prc, psc, rcnt, scnt, roffg, soffg, rowoff, csr16,
                       x, weight, bias, h16);
    hipLaunchKernelGGL(gather_kernel, dim3((N_NODES + 3) / 4), dim3(256), 0, stream,
                       h16, rowoff, csr16, out);
}